// Round 1
// baseline (546.201 us; speedup 1.0000x reference)
//
#include <hip/hip_runtime.h>
#include <hip/hip_bf16.h>

// Sorted segment-sum: out[idx[f]][d] += emb[f][d], idx sorted ascending.
// One wave (64 lanes) per chunk of FRAGS_PER_WAVE fragments; lane = dim.
// Register-accumulate runs of equal idx, atomicAdd flush on boundary.

#define FRAGS_PER_WAVE 256
#define D_EMBED 64

__global__ void seg_sum_kernel(const float* __restrict__ emb,
                               const int* __restrict__ idx,
                               float* __restrict__ out,
                               int n_frag) {
    const int gtid  = blockIdx.x * blockDim.x + threadIdx.x;
    const int wave  = gtid >> 6;          // global wave id
    const int lane  = threadIdx.x & 63;   // dim index

    long start = (long)wave * FRAGS_PER_WAVE;
    if (start >= n_frag) return;
    long end = start + FRAGS_PER_WAVE;
    if (end > n_frag) end = n_frag;

    int   cur = idx[start];
    float acc = 0.0f;

    for (long f = start; f < end; ++f) {
        int s = idx[f];                   // uniform across wave (same f)
        if (s != cur) {                   // wave-uniform branch
            atomicAdd(&out[(long)cur * D_EMBED + lane], acc);
            acc = 0.0f;
            cur = s;
        }
        acc += emb[f * D_EMBED + lane];   // coalesced: 64 lanes x 4B = 256B
    }
    atomicAdd(&out[(long)cur * D_EMBED + lane], acc);
}

extern "C" void kernel_launch(void* const* d_in, const int* in_sizes, int n_in,
                              void* d_out, int out_size, void* d_ws, size_t ws_size,
                              hipStream_t stream) {
    const float* emb = (const float*)d_in[0];
    const int*   idx = (const int*)d_in[1];
    float*       out = (float*)d_out;

    const int n_frag = in_sizes[0] / D_EMBED;   // 4,000,000

    // Output must be zeroed every call (segments with no fragments -> 0,
    // and the harness does not re-poison between timed replays).
    hipMemsetAsync(d_out, 0, (size_t)out_size * sizeof(float), stream);

    const int n_waves  = (n_frag + FRAGS_PER_WAVE - 1) / FRAGS_PER_WAVE;
    const int block    = 256;                    // 4 waves / block
    const int waves_pb = block / 64;
    const int grid     = (n_waves + waves_pb - 1) / waves_pb;

    seg_sum_kernel<<<grid, block, 0, stream>>>(emb, idx, out, n_frag);
}